// Round 14
// baseline (12311.314 us; speedup 1.0000x reference)
//
#include <hip/hip_runtime.h>

typedef __attribute__((ext_vector_type(8))) short bf16x8;
typedef __attribute__((ext_vector_type(4))) float f32x4;
typedef unsigned short u16;
typedef unsigned int u32;

#define DT_ (10.0f / 9.0f)

__device__ __forceinline__ u16 f2bf(float f) {
  u32 u = __float_as_uint(f);
  u = (u + 0x7FFFu + ((u >> 16) & 1u)) >> 16;
  return (u16)u;
}

__device__ __forceinline__ float tanh_fast(float x) {
  float ax = fabsf(x);
  float e = __expf(-2.0f * ax);
  float t = (1.0f - e) / (1.0f + e);
  return (x < 0.0f) ? -t : t;
}

// A/B fragment read from LDS: row-major [rows][K], row stride strideB bytes,
// XOR-swizzled with ((row&7)<<4).
__device__ __forceinline__ bf16x8 frag_lds(const u16* Mb, int row0, int kE, int strideB) {
  const int l = threadIdx.x & 63;
  const int r = row0 + (l & 15);
  const int kb = (kE + ((l >> 4) << 3)) << 1;
  const int off = r * strideB + (kb ^ ((r & 7) << 4));
  return *(const bf16x8*)((const char*)Mb + off);
}

// B-operand fragment straight from global W^T (row-major [N][K], bf16).
__device__ __forceinline__ bf16x8 frag_glb(const u16* WT, int col0, int kE, int K) {
  const int l = threadIdx.x & 63;
  const int j = col0 + (l & 15);
  const int k = kE + ((l >> 4) << 3);
  return *(const bf16x8*)(WT + j * K + k);
}

// Two-column-block pass (R12 workhorse): 8 waves as 2(m) x 4(n); wave m-tile 64.
// k-loop unroll-1 ON PURPOSE (R11 lesson: full unroll hoists loads and spills).
template <int KST, bool BLDS>
__device__ __forceinline__ void gemm2(f32x4 (&acc)[4][2], const u16* Ab, int aStrideB, int mb,
                                      const u16* Bp, int bK, int nb) {
#pragma unroll
  for (int mt = 0; mt < 4; ++mt)
#pragma unroll
    for (int nt = 0; nt < 2; ++nt) acc[mt][nt] = (f32x4){0.f, 0.f, 0.f, 0.f};
#pragma unroll 1
  for (int ks = 0; ks < KST; ++ks) {
    const int kE = ks * 32;
    bf16x8 bv[2];
#pragma unroll
    for (int nt = 0; nt < 2; ++nt) {
      if constexpr (BLDS) bv[nt] = frag_lds(Bp, nb + nt * 16, kE, 256);
      else                bv[nt] = frag_glb(Bp, nb + nt * 16, kE, bK);
    }
    bf16x8 av[4];
#pragma unroll
    for (int mt = 0; mt < 4; ++mt) av[mt] = frag_lds(Ab, mb + mt * 16, kE, aStrideB);
#pragma unroll
    for (int nt = 0; nt < 2; ++nt)
#pragma unroll
      for (int mt = 0; mt < 4; ++mt)
        acc[mt][nt] = __builtin_amdgcn_mfma_f32_16x16x32_bf16(av[mt], bv[nt], acc[mt][nt], 0, 0, 0);
  }
}

// Single-column-block pass (F-dim stages): acc[4].
template <int KST, bool BLDS>
__device__ __forceinline__ void gemm1(f32x4 (&acc)[4], const u16* Ab, int aStrideB, int mb,
                                      const u16* Bp, int bK, int nb) {
#pragma unroll
  for (int mt = 0; mt < 4; ++mt) acc[mt] = (f32x4){0.f, 0.f, 0.f, 0.f};
#pragma unroll 1
  for (int ks = 0; ks < KST; ++ks) {
    const int kE = ks * 32;
    bf16x8 bv;
    if constexpr (BLDS) bv = frag_lds(Bp, nb, kE, 256);
    else                bv = frag_glb(Bp, nb, kE, bK);
    bf16x8 av[4];
#pragma unroll
    for (int mt = 0; mt < 4; ++mt) av[mt] = frag_lds(Ab, mb + mt * 16, kE, aStrideB);
#pragma unroll
    for (int mt = 0; mt < 4; ++mt)
      acc[mt] = __builtin_amdgcn_mfma_f32_16x16x32_bf16(av[mt], bv, acc[mt], 0, 0, 0);
  }
}

__device__ __forceinline__ void epi_T2(const f32x4 (&acc)[4][2], u16* Q, int nb, int mb, int lane) {
  const int l15 = lane & 15, lg = lane >> 4;
#pragma unroll
  for (int nt = 0; nt < 2; ++nt) {
    const int c = nb + nt * 16 + l15;
    const int swz = (c & 7) << 4;
    char* rowp = (char*)Q + c * 256;
#pragma unroll
    for (int mt = 0; mt < 4; ++mt) {
      f32x4 v = acc[mt][nt];
      const int r0 = mb + mt * 16 + (lg << 2);
      uint2 pk;
      pk.x = (u32)f2bf(v.x) | ((u32)f2bf(v.y) << 16);
      pk.y = (u32)f2bf(v.z) | ((u32)f2bf(v.w) << 16);
      *(uint2*)(rowp + ((r0 << 1) ^ swz)) = pk;
    }
  }
}

__device__ __forceinline__ void epi_T1(const f32x4 (&acc)[4], u16* Q, int col, int mb, int lane) {
  const int l15 = lane & 15, lg = lane >> 4;
  const int c = col + l15;
  const int swz = (c & 7) << 4;
  char* rowp = (char*)Q + c * 256;
#pragma unroll
  for (int mt = 0; mt < 4; ++mt) {
    f32x4 v = acc[mt];
    const int r0 = mb + mt * 16 + (lg << 2);
    uint2 pk;
    pk.x = (u32)f2bf(v.x) | ((u32)f2bf(v.y) << 16);
    pk.y = (u32)f2bf(v.z) | ((u32)f2bf(v.w) << 16);
    *(uint2*)(rowp + ((r0 << 1) ^ swz)) = pk;
  }
}

__device__ __forceinline__ void epi_H2(const f32x4 (&acc)[4][2], u16* P, const float* __restrict__ b,
                                       int nb, int mb, int lane) {
  const int l15 = lane & 15, lg = lane >> 4;
#pragma unroll
  for (int nt = 0; nt < 2; ++nt) {
    const int c = nb + nt * 16 + l15;
    const float bb = b[c];
#pragma unroll
    for (int mt = 0; mt < 4; ++mt) {
      f32x4 v = acc[mt][nt];
      const int r0 = mb + mt * 16 + (lg << 2);
#pragma unroll
      for (int e = 0; e < 4; ++e) {
        const int r = r0 + e;
        const float h = tanh_fast(v[e] + bb);
        *(u16*)((char*)P + r * 512 + ((c << 1) ^ ((r & 7) << 4))) = f2bf(h);
      }
    }
  }
}

// Pairwise half-exchange through global ws. Producer writes its contiguous half-slice
// (BPR bytes per row, 128 rows) to Xme, releases wflag; waits partner's wflag; all
// threads fence (invalidate stale L1/L2 lines from prior fevals), copy partner slice
// into LDS; ack via rflag. Buffer reuse period = 3 phases -> pre-write ack wait (n-2).
template <int BPR, int STRIDE>
__device__ __forceinline__ void xchg(int n, u16* P, int ownOff, int othOff,
                                     uint4* __restrict__ Xme, const uint4* __restrict__ Xpt,
                                     u32* wMe, u32* wPt, u32* rMe, u32* rPt, int tid) {
  constexpr int CH = BPR / 16;
  constexpr int SH = (CH == 8) ? 3 : 4;
  constexpr int TOT = 128 * CH;
  if (n >= 3) {
    if (tid == 0) {
      while (__hip_atomic_load(rPt, __ATOMIC_ACQUIRE, __HIP_MEMORY_SCOPE_AGENT) < (u32)(n - 2))
        __builtin_amdgcn_s_sleep(1);
    }
    __syncthreads();
  }
#pragma unroll 1
  for (int i = tid; i < TOT; i += 512) {
    const int row = i >> SH;
    const int ch = i & (CH - 1);
    Xme[i] = *(const uint4*)((const char*)P + row * STRIDE + ownOff + ch * 16);
  }
  __threadfence();
  __syncthreads();
  if (tid == 0) {
    __hip_atomic_fetch_add(wMe, 1u, __ATOMIC_RELEASE, __HIP_MEMORY_SCOPE_AGENT);
    while (__hip_atomic_load(wPt, __ATOMIC_ACQUIRE, __HIP_MEMORY_SCOPE_AGENT) < (u32)(n + 1))
      __builtin_amdgcn_s_sleep(1);
  }
  __syncthreads();
  __threadfence();
#pragma unroll 1
  for (int i = tid; i < TOT; i += 512) {
    const int row = i >> SH;
    const int ch = i & (CH - 1);
    *(uint4*)((char*)P + row * STRIDE + othOff + ch * 16) = Xpt[i];
  }
  __syncthreads();
  if (tid == 0)
    __hip_atomic_fetch_add(rMe, 1u, __ATOMIC_RELEASE, __HIP_MEMORY_SCOPE_AGENT);
}

// One f(z) eval, column-split across a block pair. Block covers HID cols
// [half*128,+128) and F cols [half*64,+64). 3 exchanges: h1, h2, z.
template <int E>
__device__ __forceinline__ void feval(int fe, int step,
    u16* P, u16* Q, const u16* As,
    const u16* __restrict__ W1T, const u16* __restrict__ W2T, const u16* __restrict__ W3T,
    const float* __restrict__ b1, const float* __restrict__ b2, const float* __restrict__ b3,
    f32x4* __restrict__ SA, f32x4* __restrict__ SB,
    float* __restrict__ out,
    uint4* XH1me, const uint4* XH1pt, uint4* XH2me, const uint4* XH2pt,
    uint4* XZme, const uint4* XZpt,
    u32* wMe, u32* wPt, u32* rMe, u32* rPt,
    int batch, int half, int tid, int lane, int mb, int wn) {
  const int l15 = lane & 15, lg = lane >> 4;
  const int hb = half * 128;
  const int fb = half * 64;

  { // s1: t1 = z @ W1 (own 128 HID cols) -> Q
    f32x4 acc[4][2];
    gemm2<4, false>(acc, P, 256, mb, W1T, 128, hb + wn * 32);
    epi_T2(acc, Q, hb + wn * 32, mb, lane);
  }
  __syncthreads();
  { // s2: h1 = tanh(A @ t1 + b1) -> P (own half bytes of each 512B row)
    f32x4 acc[4][2];
    gemm2<4, true>(acc, As, 256, mb, Q, 0, hb + wn * 32);
    epi_H2(acc, P, b1, hb + wn * 32, mb, lane);
  }
  __syncthreads();
  xchg<256, 512>(fe * 3 + 0, P, half * 256, (1 - half) * 256, XH1me, XH1pt, wMe, wPt, rMe, rPt, tid);
  { // s3: t2 = h1 @ W2 (K=256 full h1) -> Q
    f32x4 acc[4][2];
    gemm2<8, false>(acc, P, 512, mb, W2T, 256, hb + wn * 32);
    epi_T2(acc, Q, hb + wn * 32, mb, lane);
  }
  __syncthreads();
  { // s4: h2 = tanh(A @ t2 + b2) -> P
    f32x4 acc[4][2];
    gemm2<4, true>(acc, As, 256, mb, Q, 0, hb + wn * 32);
    epi_H2(acc, P, b2, hb + wn * 32, mb, lane);
  }
  __syncthreads();
  xchg<256, 512>(fe * 3 + 1, P, half * 256, (1 - half) * 256, XH2me, XH2pt, wMe, wPt, rMe, rPt, tid);
  { // s5: t3 = h2 @ W3 (own 64 F cols, K=256 full h2) -> Q
    f32x4 acc[4];
    gemm1<8, false>(acc, P, 512, mb, W3T, 256, fb + wn * 16);
    epi_T1(acc, Q, fb + wn * 16, mb, lane);
  }
  __syncthreads();
  { // s6: k = A @ t3 + b3 (own 64 F cols) + fused RK epilogue (slab state)
    f32x4 ya[4], ba[4];
#pragma unroll
    for (int q = 0; q < 4; ++q) ya[q] = SA[q * 512 + tid];
    if constexpr (E == 2 || E == 3) {
#pragma unroll
      for (int q = 0; q < 4; ++q) ba[q] = SB[q * 512 + tid];
    }
    f32x4 acc[4];
    gemm1<4, true>(acc, As, 256, mb, Q, 0, fb + wn * 16);
    const int c = fb + wn * 16 + l15;
    const float bb = b3[c];
#pragma unroll
    for (int mt = 0; mt < 4; ++mt) {
      f32x4 v = acc[mt];
      const int r0 = mb + mt * 16 + (lg << 2);
      f32x4 wa, wb;
#pragma unroll
      for (int e = 0; e < 4; ++e) {
        const int r = r0 + e;
        const float kv = v[e] + bb;
        float z;
        if constexpr (E == 1) {
          wb[e] = kv;                                       // k1 -> SB
          z = ya[mt][e] + (DT_ * (1.0f / 3.0f)) * kv;
        } else if constexpr (E == 2) {
          const float k1 = ba[mt][e];
          const float y = ya[mt][e];
          z = y + DT_ * (kv - k1 * (1.0f / 3.0f));
          wb[e] = y + DT_ * (k1 - kv);                      // U -> SB
          wa[e] = y + (DT_ * 0.125f) * (k1 + 3.0f * kv);    // V -> SA
        } else if constexpr (E == 3) {
          z = ba[mt][e] + DT_ * kv;                         // z4 = U + dt*k3
          wa[e] = ya[mt][e] + (DT_ * 0.375f) * kv;          // W -> SA
        } else {
          const float yn = ya[mt][e] + (DT_ * 0.125f) * kv;
          wa[e] = yn;                                       // yn -> SA
          __builtin_nontemporal_store(yn, &out[batch * 163840 + r * 1280 + (step + 1) * 128 + c]);
          z = yn;
        }
        *(u16*)((char*)P + r * 256 + ((c << 1) ^ ((r & 7) << 4))) = f2bf(z);
      }
      if constexpr (E == 1 || E == 2) SB[mt * 512 + tid] = wb;
      if constexpr (E != 1) SA[mt * 512 + tid] = wa;
    }
  }
  __syncthreads();
  xchg<128, 256>(fe * 3 + 2, P, half * 128, (1 - half) * 128, XZme, XZpt, wMe, wPt, rMe, rPt, tid);
}

__global__ __launch_bounds__(512, 2)
void ode_main(
    const u16* __restrict__ Aswz,
    const u16* __restrict__ W1T, const u16* __restrict__ W2T, const u16* __restrict__ W3T,
    const float* __restrict__ b1, const float* __restrict__ b2, const float* __restrict__ b3,
    const float* __restrict__ x,
    f32x4* __restrict__ KS, uint4* __restrict__ XH1, uint4* __restrict__ XH2,
    uint4* __restrict__ XZ, u32* __restrict__ flags,
    float* __restrict__ out) {
  __shared__ u16 P[32768];   // 64 KB: activations node-major / z
  __shared__ u16 Q[32768];   // 64 KB: transposed intermediates t^T
  __shared__ u16 As[16384];  // 32 KB: adjacency, pre-swizzled
  const int tid = threadIdx.x;
  const int lane = tid & 63;
  const int wid = tid >> 6;
  const int wm = wid >> 2, wn = wid & 3;
  const int mb = wm * 64;
  const int l15 = lane & 15, lg = lane >> 4;
  const int bid = blockIdx.x;
  const int batch = bid & 127;
  const int half = bid >> 7;
  const int pid = bid ^ 128;   // partner: same XCD if mapping is bid%8

  f32x4* SA = KS + bid * 4096;          // 32 KB slab: y/V/W/yn (own F-half)
  f32x4* SB = SA + 2048;                // 32 KB slab: k1/U
  uint4* XH1me = XH1 + bid * 2048;  const uint4* XH1pt = XH1 + pid * 2048;
  uint4* XH2me = XH2 + bid * 2048;  const uint4* XH2pt = XH2 + pid * 2048;
  uint4* XZme  = XZ  + bid * 1024;  const uint4* XZpt  = XZ  + pid * 1024;
  u32* wMe = flags + bid;       u32* wPt = flags + pid;
  u32* rMe = flags + 256 + bid; u32* rPt = flags + 256 + pid;

  { // stage adjacency into LDS; 2048 uint4
    const uint4* s = (const uint4*)Aswz;
    uint4* d = (uint4*)As;
#pragma unroll
    for (int i = 0; i < 4; ++i) d[tid + i * 512] = s[tid + i * 512];
  }

  // init: full z into P (both halves from x); own half -> SA slab + out step-0.
#pragma unroll 1
  for (int hh = 0; hh < 2; ++hh) {
    const int c = hh * 64 + wn * 16 + l15;
#pragma unroll 1
    for (int mt = 0; mt < 4; ++mt) {
      f32x4 w;
#pragma unroll
      for (int e = 0; e < 4; ++e) {
        const int r = mb + mt * 16 + (lg << 2) + e;
        const float v = x[((batch * 128 + r) * 12 + 11) * 128 + c];
        w[e] = v;
        *(u16*)((char*)P + r * 256 + ((c << 1) ^ ((r & 7) << 4))) = f2bf(v);
        if (hh == half) __builtin_nontemporal_store(v, &out[batch * 163840 + r * 1280 + c]);
      }
      if (hh == half) SA[mt * 512 + tid] = w;
    }
  }
  __syncthreads();

  for (int s = 0; s < 9; ++s) {
    const int f0 = s * 4;
    feval<1>(f0 + 0, s, P, Q, As, W1T, W2T, W3T, b1, b2, b3, SA, SB, out,
             XH1me, XH1pt, XH2me, XH2pt, XZme, XZpt, wMe, wPt, rMe, rPt,
             batch, half, tid, lane, mb, wn);
    feval<2>(f0 + 1, s, P, Q, As, W1T, W2T, W3T, b1, b2, b3, SA, SB, out,
             XH1me, XH1pt, XH2me, XH2pt, XZme, XZpt, wMe, wPt, rMe, rPt,
             batch, half, tid, lane, mb, wn);
    feval<3>(f0 + 2, s, P, Q, As, W1T, W2T, W3T, b1, b2, b3, SA, SB, out,
             XH1me, XH1pt, XH2me, XH2pt, XZme, XZpt, wMe, wPt, rMe, rPt,
             batch, half, tid, lane, mb, wn);
    feval<4>(f0 + 3, s, P, Q, As, W1T, W2T, W3T, b1, b2, b3, SA, SB, out,
             XH1me, XH1pt, XH2me, XH2pt, XZme, XZpt, wMe, wPt, rMe, rPt,
             batch, half, tid, lane, mb, wn);
  }
}

// ---- prep kernels ----

__global__ void prep_adj_k(const float* __restrict__ adjw, u16* __restrict__ Aswz) {
  const int n = blockIdx.x;
  const int m = threadIdx.x;
  const float w = adjw[n * 128 + m];
  const float sg = 1.0f / (1.0f + __expf(-w));
  float s = sg;
#pragma unroll
  for (int o = 1; o < 64; o <<= 1) s += __shfl_xor(s, o);
  __shared__ float red[2];
  if ((m & 63) == 0) red[m >> 6] = s;
  __syncthreads();
  const float deg = fmaxf(red[0] + red[1], 1.0f);
  const float v = sg / deg;
  *(u16*)((char*)Aswz + n * 256 + ((m << 1) ^ ((n & 7) << 4))) = f2bf(v);
}

__global__ void prep_w_k(const float* __restrict__ W1, const float* __restrict__ W2,
                         const float* __restrict__ W3,
                         u16* __restrict__ W1T, u16* __restrict__ W2T, u16* __restrict__ W3T) {
  const int i = blockIdx.x * 256 + threadIdx.x;
  if (i < 32768) {
    W1T[i] = f2bf(W1[(i & 127) * 256 + (i >> 7)]);
    W3T[i] = f2bf(W3[(i & 255) * 128 + (i >> 8)]);
  }
  if (i < 65536) W2T[i] = f2bf(W2[(i & 255) * 256 + (i >> 8)]);
}

extern "C" void kernel_launch(void* const* d_in, const int* in_sizes, int n_in,
                              void* d_out, int out_size, void* d_ws, size_t ws_size,
                              hipStream_t stream) {
  const float* x    = (const float*)d_in[0];
  const float* adjw = (const float*)d_in[1];
  const float* W1   = (const float*)d_in[2];
  const float* b1   = (const float*)d_in[3];
  const float* W2   = (const float*)d_in[4];
  const float* b2   = (const float*)d_in[5];
  const float* W3   = (const float*)d_in[6];
  const float* b3   = (const float*)d_in[7];
  float* out = (float*)d_out;

  u16* Aswz = (u16*)d_ws;
  u16* W1T = Aswz + 16384;
  u16* W2T = W1T + 32768;
  u16* W3T = W2T + 65536;
  f32x4* KS = (f32x4*)(W3T + 32768);        // 256 blocks x 64 KB = 16 MB
  uint4* XH1 = (uint4*)(KS + 256 * 4096);   // 8 MB
  uint4* XH2 = XH1 + 256 * 2048;            // 8 MB
  uint4* XZ  = XH2 + 256 * 2048;            // 4 MB
  u32* flags = (u32*)(XZ + 256 * 1024);     // 2 KB (wflag[256] + rflag[256])

  hipMemsetAsync(flags, 0, 512 * sizeof(u32), stream);
  prep_adj_k<<<128, 128, 0, stream>>>(adjw, Aswz);
  prep_w_k<<<256, 256, 0, stream>>>(W1, W2, W3, W1T, W2T, W3T);
  ode_main<<<256, 512, 0, stream>>>(Aswz, W1T, W2T, W3T, b1, b2, b3, x,
                                    KS, XH1, XH2, XZ, flags, out);
}

// Round 15
// 1121.584 us; speedup vs baseline: 10.9767x; 10.9767x over previous
//
#include <hip/hip_runtime.h>

typedef __attribute__((ext_vector_type(8))) short bf16x8;
typedef __attribute__((ext_vector_type(4))) float f32x4;
typedef unsigned short u16;
typedef unsigned int u32;

#define DT_ (10.0f / 9.0f)

__device__ __forceinline__ u16 f2bf(float f) {
  u32 u = __float_as_uint(f);
  u = (u + 0x7FFFu + ((u >> 16) & 1u)) >> 16;
  return (u16)u;
}

__device__ __forceinline__ float tanh_fast(float x) {
  float ax = fabsf(x);
  float e = __expf(-2.0f * ax);
  float t = (1.0f - e) / (1.0f + e);
  return (x < 0.0f) ? -t : t;
}

// A/B fragment read from LDS: row-major [rows][K], row stride strideB bytes,
// XOR-swizzled with ((row&7)<<4).
__device__ __forceinline__ bf16x8 frag_lds(const u16* Mb, int row0, int kE, int strideB) {
  const int l = threadIdx.x & 63;
  const int r = row0 + (l & 15);
  const int kb = (kE + ((l >> 4) << 3)) << 1;
  const int off = r * strideB + (kb ^ ((r & 7) << 4));
  return *(const bf16x8*)((const char*)Mb + off);
}

// B-operand fragment straight from global W^T (row-major [N][K], bf16).
__device__ __forceinline__ bf16x8 frag_glb(const u16* WT, int col0, int kE, int K) {
  const int l = threadIdx.x & 63;
  const int j = col0 + (l & 15);
  const int k = kE + ((l >> 4) << 3);
  return *(const bf16x8*)(WT + j * K + k);
}

// Two-column-block pass, SOFTWARE-PIPELINED 2-deep: prefetch k+1 fragments while
// k's MFMAs run (hides ~120cy LDS / ~200cy L2 latency behind the MFMA burst).
// Explicit ping-pong buffers with STATIC indices (runtime-indexed arrays -> scratch).
// Outer loop unroll-1 (R11 lesson: full unroll hoists all loads and spills).
template <int KST, bool BLDS>
__device__ __forceinline__ void gemm2(f32x4 (&acc)[4][2], const u16* Ab, int aStrideB, int mb,
                                      const u16* Bp, int bK, int nb) {
#pragma unroll
  for (int mt = 0; mt < 4; ++mt)
#pragma unroll
    for (int nt = 0; nt < 2; ++nt) acc[mt][nt] = (f32x4){0.f, 0.f, 0.f, 0.f};
  bf16x8 av0[4], bv0[2], av1[4], bv1[2];
#pragma unroll
  for (int nt = 0; nt < 2; ++nt) {
    if constexpr (BLDS) bv0[nt] = frag_lds(Bp, nb + nt * 16, 0, 256);
    else                bv0[nt] = frag_glb(Bp, nb + nt * 16, 0, bK);
  }
#pragma unroll
  for (int mt = 0; mt < 4; ++mt) av0[mt] = frag_lds(Ab, mb + mt * 16, 0, aStrideB);
#pragma unroll 1
  for (int ks = 0; ks < KST; ks += 2) {
    const int k1 = (ks + 1) * 32;
#pragma unroll
    for (int nt = 0; nt < 2; ++nt) {
      if constexpr (BLDS) bv1[nt] = frag_lds(Bp, nb + nt * 16, k1, 256);
      else                bv1[nt] = frag_glb(Bp, nb + nt * 16, k1, bK);
    }
#pragma unroll
    for (int mt = 0; mt < 4; ++mt) av1[mt] = frag_lds(Ab, mb + mt * 16, k1, aStrideB);
#pragma unroll
    for (int nt = 0; nt < 2; ++nt)
#pragma unroll
      for (int mt = 0; mt < 4; ++mt)
        acc[mt][nt] = __builtin_amdgcn_mfma_f32_16x16x32_bf16(av0[mt], bv0[nt], acc[mt][nt], 0, 0, 0);
    if (ks + 2 < KST) {
      const int k2 = (ks + 2) * 32;
#pragma unroll
      for (int nt = 0; nt < 2; ++nt) {
        if constexpr (BLDS) bv0[nt] = frag_lds(Bp, nb + nt * 16, k2, 256);
        else                bv0[nt] = frag_glb(Bp, nb + nt * 16, k2, bK);
      }
#pragma unroll
      for (int mt = 0; mt < 4; ++mt) av0[mt] = frag_lds(Ab, mb + mt * 16, k2, aStrideB);
    }
#pragma unroll
    for (int nt = 0; nt < 2; ++nt)
#pragma unroll
      for (int mt = 0; mt < 4; ++mt)
        acc[mt][nt] = __builtin_amdgcn_mfma_f32_16x16x32_bf16(av1[mt], bv1[nt], acc[mt][nt], 0, 0, 0);
  }
}

// Single-column-block pass (stage 5/6), same 2-deep pipeline.
template <int KST, bool BLDS>
__device__ __forceinline__ void gemm1(f32x4 (&acc)[4], const u16* Ab, int aStrideB, int mb,
                                      const u16* Bp, int bK, int nb) {
#pragma unroll
  for (int mt = 0; mt < 4; ++mt) acc[mt] = (f32x4){0.f, 0.f, 0.f, 0.f};
  bf16x8 av0[4], av1[4];
  bf16x8 bv0, bv1;
  if constexpr (BLDS) bv0 = frag_lds(Bp, nb, 0, 256);
  else                bv0 = frag_glb(Bp, nb, 0, bK);
#pragma unroll
  for (int mt = 0; mt < 4; ++mt) av0[mt] = frag_lds(Ab, mb + mt * 16, 0, aStrideB);
#pragma unroll 1
  for (int ks = 0; ks < KST; ks += 2) {
    const int k1 = (ks + 1) * 32;
    if constexpr (BLDS) bv1 = frag_lds(Bp, nb, k1, 256);
    else                bv1 = frag_glb(Bp, nb, k1, bK);
#pragma unroll
    for (int mt = 0; mt < 4; ++mt) av1[mt] = frag_lds(Ab, mb + mt * 16, k1, aStrideB);
#pragma unroll
    for (int mt = 0; mt < 4; ++mt)
      acc[mt] = __builtin_amdgcn_mfma_f32_16x16x32_bf16(av0[mt], bv0, acc[mt], 0, 0, 0);
    if (ks + 2 < KST) {
      const int k2 = (ks + 2) * 32;
      if constexpr (BLDS) bv0 = frag_lds(Bp, nb, k2, 256);
      else                bv0 = frag_glb(Bp, nb, k2, bK);
#pragma unroll
      for (int mt = 0; mt < 4; ++mt) av0[mt] = frag_lds(Ab, mb + mt * 16, k2, aStrideB);
    }
#pragma unroll
    for (int mt = 0; mt < 4; ++mt)
      acc[mt] = __builtin_amdgcn_mfma_f32_16x16x32_bf16(av1[mt], bv1, acc[mt], 0, 0, 0);
  }
}

// Write acc[4][2] transposed (t^T) into Q: Q[col(feature)][node], row stride 256 B, swizzled.
__device__ __forceinline__ void epi_T2(const f32x4 (&acc)[4][2], u16* Q, int nb, int mb, int lane) {
  const int l15 = lane & 15, lg = lane >> 4;
#pragma unroll
  for (int nt = 0; nt < 2; ++nt) {
    const int c = nb + nt * 16 + l15;
    const int swz = (c & 7) << 4;
    char* rowp = (char*)Q + c * 256;
#pragma unroll
    for (int mt = 0; mt < 4; ++mt) {
      f32x4 v = acc[mt][nt];
      const int r0 = mb + mt * 16 + (lg << 2);
      uint2 pk;
      pk.x = (u32)f2bf(v.x) | ((u32)f2bf(v.y) << 16);
      pk.y = (u32)f2bf(v.z) | ((u32)f2bf(v.w) << 16);
      *(uint2*)(rowp + ((r0 << 1) ^ swz)) = pk;
    }
  }
}

// Bias (from global) + tanh + write node-major into P (row stride 512 B, swizzled).
__device__ __forceinline__ void epi_H2(const f32x4 (&acc)[4][2], u16* P, const float* __restrict__ b,
                                       int nb, int mb, int lane) {
  const int l15 = lane & 15, lg = lane >> 4;
#pragma unroll
  for (int nt = 0; nt < 2; ++nt) {
    const int c = nb + nt * 16 + l15;
    const float bb = b[c];
#pragma unroll
    for (int mt = 0; mt < 4; ++mt) {
      f32x4 v = acc[mt][nt];
      const int r0 = mb + mt * 16 + (lg << 2);
#pragma unroll
      for (int e = 0; e < 4; ++e) {
        const int r = r0 + e;
        const float h = tanh_fast(v[e] + bb);
        *(u16*)((char*)P + r * 512 + ((c << 1) ^ ((r & 7) << 4))) = f2bf(h);
      }
    }
  }
}

// One f(z) evaluation; z (bf16, node-major, stride 256B, swizzled) in P on entry.
// ZERO persistent register state. RK state in ws slabs (per-thread coalesced):
//   SA: y -> V -> W -> yn      SB: k1 -> U
// Loaded/stored only in the stage-6 epilogue. Same f32 ops as R10/R12.
template <int E>
__device__ __forceinline__ void feval(int step,
    u16* P, u16* Q, const u16* As,
    const u16* __restrict__ W1T, const u16* __restrict__ W2T, const u16* __restrict__ W3T,
    const float* __restrict__ b1, const float* __restrict__ b2, const float* __restrict__ b3,
    f32x4* __restrict__ SA, f32x4* __restrict__ SB,
    float* __restrict__ out,
    int batch, int tid, int lane, int mb, int wn) {
  const int l15 = lane & 15, lg = lane >> 4;

  // stage 1: t1 = z @ W1   [M128 N256 K128] -> Q (t^T)
#pragma unroll 1
  for (int h = 0; h < 2; ++h) {
    f32x4 acc[4][2];
    gemm2<4, false>(acc, P, 256, mb, W1T, 128, wn * 64 + h * 32);
    epi_T2(acc, Q, wn * 64 + h * 32, mb, lane);
  }
  __syncthreads();
  // stage 2: h1 = tanh(A @ t1 + b1) -> P node-major (stride 512)
#pragma unroll 1
  for (int h = 0; h < 2; ++h) {
    f32x4 acc[4][2];
    gemm2<4, true>(acc, As, 256, mb, Q, 0, wn * 64 + h * 32);
    epi_H2(acc, P, b1, wn * 64 + h * 32, mb, lane);
  }
  __syncthreads();
  // stage 3: t2 = h1 @ W2  [M128 N256 K256] -> Q (t^T)
#pragma unroll 1
  for (int h = 0; h < 2; ++h) {
    f32x4 acc[4][2];
    gemm2<8, false>(acc, P, 512, mb, W2T, 256, wn * 64 + h * 32);
    epi_T2(acc, Q, wn * 64 + h * 32, mb, lane);
  }
  __syncthreads();
  // stage 4: h2 = tanh(A @ t2 + b2) -> P node-major
#pragma unroll 1
  for (int h = 0; h < 2; ++h) {
    f32x4 acc[4][2];
    gemm2<4, true>(acc, As, 256, mb, Q, 0, wn * 64 + h * 32);
    epi_H2(acc, P, b2, wn * 64 + h * 32, mb, lane);
  }
  __syncthreads();
  { // stage 5: t3 = h2 @ W3  [M128 N128 K256] -> Q rows 0..127
    f32x4 acc[4][2];
    gemm2<8, false>(acc, P, 512, mb, W3T, 256, wn * 32);
    epi_T2(acc, Q, wn * 32, mb, lane);
  }
  __syncthreads();

  // stage 6: k = A @ t3 + b3 [M128 N128 K128] + fused RK epilogue (state streamed
  // from/to ws slabs; loads issued before the GEMM -> latency covered)
#pragma unroll 1
  for (int p = 0; p < 2; ++p) {
    // state loads for this half (16 + 16 floats transient)
    f32x4 ya[4], ba[4];
#pragma unroll
    for (int q = 0; q < 4; ++q) ya[q] = SA[(p * 4 + q) * 512 + tid];
    if constexpr (E == 2 || E == 3) {
#pragma unroll
      for (int q = 0; q < 4; ++q) ba[q] = SB[(p * 4 + q) * 512 + tid];
    }
    f32x4 acc[4];
    gemm1<4, true>(acc, As, 256, mb, Q, 0, wn * 32 + p * 16);
    const int c = wn * 32 + p * 16 + l15;
    const float bb = b3[c];
#pragma unroll
    for (int mt = 0; mt < 4; ++mt) {
      f32x4 v = acc[mt];
      const int r0 = mb + mt * 16 + (lg << 2);
      const int i4 = p * 4 + mt;
      f32x4 wa, wb;
#pragma unroll
      for (int e = 0; e < 4; ++e) {
        const int r = r0 + e;
        const float kv = v[e] + bb;
        float z;
        if constexpr (E == 1) {
          wb[e] = kv;                                   // k1 -> SB
          z = ya[mt][e] + (DT_ * (1.0f / 3.0f)) * kv;
        } else if constexpr (E == 2) {
          const float k1 = ba[mt][e];
          const float y = ya[mt][e];
          z = y + DT_ * (kv - k1 * (1.0f / 3.0f));
          wb[e] = y + DT_ * (k1 - kv);                  // U -> SB
          wa[e] = y + (DT_ * 0.125f) * (k1 + 3.0f * kv);  // V -> SA
        } else if constexpr (E == 3) {
          z = ba[mt][e] + DT_ * kv;                     // z4 = U + dt*k3
          wa[e] = ya[mt][e] + (DT_ * 0.375f) * kv;      // W = V + 3dt/8*k3 -> SA
        } else {
          const float yn = ya[mt][e] + (DT_ * 0.125f) * kv;
          wa[e] = yn;                                   // yn -> SA
          __builtin_nontemporal_store(yn, &out[batch * 163840 + r * 1280 + (step + 1) * 128 + c]);
          z = yn;
        }
        // z for the next eval -> P (node-major, stride 256, swizzled)
        *(u16*)((char*)P + r * 256 + ((c << 1) ^ ((r & 7) << 4))) = f2bf(z);
      }
      if constexpr (E == 1 || E == 2) SB[i4 * 512 + tid] = wb;
      if constexpr (E != 1) SA[i4 * 512 + tid] = wa;
    }
  }
  __syncthreads();
}

__global__ __launch_bounds__(512, 2)  // 8-wave block, 1 block/CU -> 2 waves/EU
void ode_main(
    const u16* __restrict__ Aswz,
    const u16* __restrict__ W1T, const u16* __restrict__ W2T, const u16* __restrict__ W3T,
    const float* __restrict__ b1, const float* __restrict__ b2, const float* __restrict__ b3,
    const float* __restrict__ x,
    f32x4* __restrict__ KS,
    float* __restrict__ out) {
  __shared__ u16 P[32768];   // 64 KB: activations node-major / z
  __shared__ u16 Q[32768];   // 64 KB: transposed intermediates t^T
  __shared__ u16 As[16384];  // 32 KB: normalized adjacency, pre-swizzled
  const int tid = threadIdx.x;
  const int lane = tid & 63;
  const int wid = tid >> 6;
  const int wm = wid >> 2, wn = wid & 3;
  const int mb = wm * 64;
  const int l15 = lane & 15, lg = lane >> 4;
  const int batch = blockIdx.x;
  f32x4* SA = KS + batch * 8192;       // 64 KB slab: y / V / W / yn
  f32x4* SB = SA + 4096;               // 64 KB slab: k1 / U

  { // stage adjacency into LDS (pre-swizzled in ws -> linear copy); 2048 uint4
    const uint4* s = (const uint4*)Aswz;
    uint4* d = (uint4*)As;
#pragma unroll
    for (int i = 0; i < 4; ++i) d[tid + i * 512] = s[tid + i * 512];
  }

  // init: y0 -> SA slab; seed z into P; write out step-0 slot. No persistent regs.
#pragma unroll 1
  for (int p = 0; p < 2; ++p)
#pragma unroll 1
    for (int mt = 0; mt < 4; ++mt) {
      const int c = wn * 32 + p * 16 + l15;
      f32x4 w;
#pragma unroll
      for (int e = 0; e < 4; ++e) {
        const int r = mb + mt * 16 + (lg << 2) + e;
        const float v = x[((batch * 128 + r) * 12 + 11) * 128 + c];
        w[e] = v;
        __builtin_nontemporal_store(v, &out[batch * 163840 + r * 1280 + c]);
        *(u16*)((char*)P + r * 256 + ((c << 1) ^ ((r & 7) << 4))) = f2bf(v);
      }
      SA[(p * 4 + mt) * 512 + tid] = w;
    }
  __syncthreads();

  for (int s = 0; s < 9; ++s) {
    feval<1>(s, P, Q, As, W1T, W2T, W3T, b1, b2, b3, SA, SB, out, batch, tid, lane, mb, wn);
    feval<2>(s, P, Q, As, W1T, W2T, W3T, b1, b2, b3, SA, SB, out, batch, tid, lane, mb, wn);
    feval<3>(s, P, Q, As, W1T, W2T, W3T, b1, b2, b3, SA, SB, out, batch, tid, lane, mb, wn);
    feval<4>(s, P, Q, As, W1T, W2T, W3T, b1, b2, b3, SA, SB, out, batch, tid, lane, mb, wn);
  }
}

// ---- prep kernels ----

__global__ void prep_adj_k(const float* __restrict__ adjw, u16* __restrict__ Aswz) {
  const int n = blockIdx.x;
  const int m = threadIdx.x;  // 128 threads = 2 waves
  const float w = adjw[n * 128 + m];
  const float sg = 1.0f / (1.0f + __expf(-w));
  float s = sg;
#pragma unroll
  for (int o = 1; o < 64; o <<= 1) s += __shfl_xor(s, o);
  __shared__ float red[2];
  if ((m & 63) == 0) red[m >> 6] = s;
  __syncthreads();
  const float deg = fmaxf(red[0] + red[1], 1.0f);
  const float v = sg / deg;
  *(u16*)((char*)Aswz + n * 256 + ((m << 1) ^ ((n & 7) << 4))) = f2bf(v);
}

__global__ void prep_w_k(const float* __restrict__ W1, const float* __restrict__ W2,
                         const float* __restrict__ W3,
                         u16* __restrict__ W1T, u16* __restrict__ W2T, u16* __restrict__ W3T) {
  const int i = blockIdx.x * 256 + threadIdx.x;
  if (i < 32768) {
    W1T[i] = f2bf(W1[(i & 127) * 256 + (i >> 7)]);  // W1T[hid][f] = W1[f][hid]
    W3T[i] = f2bf(W3[(i & 255) * 128 + (i >> 8)]);  // W3T[f][hid] = W3[hid][f]
  }
  if (i < 65536) W2T[i] = f2bf(W2[(i & 255) * 256 + (i >> 8)]);  // W2T[h2][h1] = W2[h1][h2]
}

extern "C" void kernel_launch(void* const* d_in, const int* in_sizes, int n_in,
                              void* d_out, int out_size, void* d_ws, size_t ws_size,
                              hipStream_t stream) {
  const float* x    = (const float*)d_in[0];
  const float* adjw = (const float*)d_in[1];
  const float* W1   = (const float*)d_in[2];
  const float* b1   = (const float*)d_in[3];
  const float* W2   = (const float*)d_in[4];
  const float* b2   = (const float*)d_in[5];
  const float* W3   = (const float*)d_in[6];
  const float* b3   = (const float*)d_in[7];
  float* out = (float*)d_out;

  u16* Aswz = (u16*)d_ws;
  u16* W1T = Aswz + 16384;
  u16* W2T = W1T + 32768;
  u16* W3T = W2T + 65536;
  f32x4* KS = (f32x4*)(W3T + 32768);  // 128 blocks x 128 KB = 16 MB RK state slabs

  prep_adj_k<<<128, 128, 0, stream>>>(adjw, Aswz);
  prep_w_k<<<256, 256, 0, stream>>>(W1, W2, W3, W1T, W2T, W3T);
  ode_main<<<128, 512, 0, stream>>>(Aswz, W1T, W2T, W3T, b1, b2, b3, x, KS, out);
}

// Round 16
// 981.956 us; speedup vs baseline: 12.5375x; 1.1422x over previous
//
#include <hip/hip_runtime.h>
#include <hip/hip_bf16.h>

typedef __attribute__((ext_vector_type(8))) short bf16x8;
typedef __attribute__((ext_vector_type(4))) float f32x4;
typedef unsigned short u16;
typedef unsigned int u32;

#define DT_ (10.0f / 9.0f)

__device__ __forceinline__ u16 f2bf(float f) {
  u32 u = __float_as_uint(f);
  u = (u + 0x7FFFu + ((u >> 16) & 1u)) >> 16;
  return (u16)u;
}

// Packed RNE f32x2 -> bf16x2 (one v_cvt_pk_bf16_f32; bit-identical to f2bf pair).
__device__ __forceinline__ u32 cvtpk(float lo, float hi) {
  __hip_bfloat162 h = __float22bfloat162_rn(float2{lo, hi});
  return *reinterpret_cast<u32*>(&h);
}

__device__ __forceinline__ float tanh_fast(float x) {
  float ax = fabsf(x);
  float e = __expf(-2.0f * ax);
  float t = (1.0f - e) * __builtin_amdgcn_rcpf(1.0f + e);  // ~1ulp rcp vs 10-instr divide
  return copysignf(t, x);
}

// A/B fragment read from LDS: row-major [rows][K], row stride strideB bytes,
// XOR-swizzled with ((row&7)<<4).
__device__ __forceinline__ bf16x8 frag_lds(const u16* Mb, int row0, int kE, int strideB) {
  const int l = threadIdx.x & 63;
  const int r = row0 + (l & 15);
  const int kb = (kE + ((l >> 4) << 3)) << 1;
  const int off = r * strideB + (kb ^ ((r & 7) << 4));
  return *(const bf16x8*)((const char*)Mb + off);
}

// B-operand fragment straight from global W^T (row-major [N][K], bf16).
__device__ __forceinline__ bf16x8 frag_glb(const u16* WT, int col0, int kE, int K) {
  const int l = threadIdx.x & 63;
  const int j = col0 + (l & 15);
  const int k = kE + ((l >> 4) << 3);
  return *(const bf16x8*)(WT + j * K + k);
}

// Two-column-block pass, 2-deep software pipeline (R15). Outer loop unroll-1
// (R11 lesson: full unroll hoists all loads and spills past the 128-VGPR grant).
template <int KST, bool BLDS>
__device__ __forceinline__ void gemm2(f32x4 (&acc)[4][2], const u16* Ab, int aStrideB, int mb,
                                      const u16* Bp, int bK, int nb) {
#pragma unroll
  for (int mt = 0; mt < 4; ++mt)
#pragma unroll
    for (int nt = 0; nt < 2; ++nt) acc[mt][nt] = (f32x4){0.f, 0.f, 0.f, 0.f};
  bf16x8 av0[4], bv0[2], av1[4], bv1[2];
#pragma unroll
  for (int nt = 0; nt < 2; ++nt) {
    if constexpr (BLDS) bv0[nt] = frag_lds(Bp, nb + nt * 16, 0, 256);
    else                bv0[nt] = frag_glb(Bp, nb + nt * 16, 0, bK);
  }
#pragma unroll
  for (int mt = 0; mt < 4; ++mt) av0[mt] = frag_lds(Ab, mb + mt * 16, 0, aStrideB);
#pragma unroll 1
  for (int ks = 0; ks < KST; ks += 2) {
    const int k1 = (ks + 1) * 32;
#pragma unroll
    for (int nt = 0; nt < 2; ++nt) {
      if constexpr (BLDS) bv1[nt] = frag_lds(Bp, nb + nt * 16, k1, 256);
      else                bv1[nt] = frag_glb(Bp, nb + nt * 16, k1, bK);
    }
#pragma unroll
    for (int mt = 0; mt < 4; ++mt) av1[mt] = frag_lds(Ab, mb + mt * 16, k1, aStrideB);
#pragma unroll
    for (int nt = 0; nt < 2; ++nt)
#pragma unroll
      for (int mt = 0; mt < 4; ++mt)
        acc[mt][nt] = __builtin_amdgcn_mfma_f32_16x16x32_bf16(av0[mt], bv0[nt], acc[mt][nt], 0, 0, 0);
    if (ks + 2 < KST) {
      const int k2 = (ks + 2) * 32;
#pragma unroll
      for (int nt = 0; nt < 2; ++nt) {
        if constexpr (BLDS) bv0[nt] = frag_lds(Bp, nb + nt * 16, k2, 256);
        else                bv0[nt] = frag_glb(Bp, nb + nt * 16, k2, bK);
      }
#pragma unroll
      for (int mt = 0; mt < 4; ++mt) av0[mt] = frag_lds(Ab, mb + mt * 16, k2, aStrideB);
    }
#pragma unroll
    for (int nt = 0; nt < 2; ++nt)
#pragma unroll
      for (int mt = 0; mt < 4; ++mt)
        acc[mt][nt] = __builtin_amdgcn_mfma_f32_16x16x32_bf16(av1[mt], bv1[nt], acc[mt][nt], 0, 0, 0);
  }
}

// Single-column-block pass (stage 6), same 2-deep pipeline.
template <int KST, bool BLDS>
__device__ __forceinline__ void gemm1(f32x4 (&acc)[4], const u16* Ab, int aStrideB, int mb,
                                      const u16* Bp, int bK, int nb) {
#pragma unroll
  for (int mt = 0; mt < 4; ++mt) acc[mt] = (f32x4){0.f, 0.f, 0.f, 0.f};
  bf16x8 av0[4], av1[4];
  bf16x8 bv0, bv1;
  if constexpr (BLDS) bv0 = frag_lds(Bp, nb, 0, 256);
  else                bv0 = frag_glb(Bp, nb, 0, bK);
#pragma unroll
  for (int mt = 0; mt < 4; ++mt) av0[mt] = frag_lds(Ab, mb + mt * 16, 0, aStrideB);
#pragma unroll 1
  for (int ks = 0; ks < KST; ks += 2) {
    const int k1 = (ks + 1) * 32;
    if constexpr (BLDS) bv1 = frag_lds(Bp, nb, k1, 256);
    else                bv1 = frag_glb(Bp, nb, k1, bK);
#pragma unroll
    for (int mt = 0; mt < 4; ++mt) av1[mt] = frag_lds(Ab, mb + mt * 16, k1, aStrideB);
#pragma unroll
    for (int mt = 0; mt < 4; ++mt)
      acc[mt] = __builtin_amdgcn_mfma_f32_16x16x32_bf16(av0[mt], bv0, acc[mt], 0, 0, 0);
    if (ks + 2 < KST) {
      const int k2 = (ks + 2) * 32;
      if constexpr (BLDS) bv0 = frag_lds(Bp, nb, k2, 256);
      else                bv0 = frag_glb(Bp, nb, k2, bK);
#pragma unroll
      for (int mt = 0; mt < 4; ++mt) av0[mt] = frag_lds(Ab, mb + mt * 16, k2, aStrideB);
    }
#pragma unroll
    for (int mt = 0; mt < 4; ++mt)
      acc[mt] = __builtin_amdgcn_mfma_f32_16x16x32_bf16(av1[mt], bv1, acc[mt], 0, 0, 0);
  }
}

// Write acc[4][2] transposed (t^T) into Q: packed cvt_pk conversions + uint2 stores.
__device__ __forceinline__ void epi_T2(const f32x4 (&acc)[4][2], u16* Q, int nb, int mb, int lane) {
  const int l15 = lane & 15, lg = lane >> 4;
#pragma unroll
  for (int nt = 0; nt < 2; ++nt) {
    const int c = nb + nt * 16 + l15;
    const int swz = (c & 7) << 4;
    char* rowp = (char*)Q + c * 256;
#pragma unroll
    for (int mt = 0; mt < 4; ++mt) {
      f32x4 v = acc[mt][nt];
      const int r0 = mb + mt * 16 + (lg << 2);
      uint2 pk;
      pk.x = cvtpk(v.x, v.y);
      pk.y = cvtpk(v.z, v.w);
      *(uint2*)(rowp + ((r0 << 1) ^ swz)) = pk;
    }
  }
}

// Bias + tanh + node-major P write; pairwise cvt_pk, scalar u16 stores.
__device__ __forceinline__ void epi_H2(const f32x4 (&acc)[4][2], u16* P, const float* __restrict__ b,
                                       int nb, int mb, int lane) {
  const int l15 = lane & 15, lg = lane >> 4;
#pragma unroll
  for (int nt = 0; nt < 2; ++nt) {
    const int c = nb + nt * 16 + l15;
    const float bb = b[c];
    const int csh = c << 1;
#pragma unroll
    for (int mt = 0; mt < 4; ++mt) {
      f32x4 v = acc[mt][nt];
      const int r0 = mb + mt * 16 + (lg << 2);
      float t0 = tanh_fast(v.x + bb), t1 = tanh_fast(v.y + bb);
      float t2 = tanh_fast(v.z + bb), t3 = tanh_fast(v.w + bb);
      const u32 p01 = cvtpk(t0, t1);
      const u32 p23 = cvtpk(t2, t3);
      *(u16*)((char*)P + (r0 + 0) * 512 + (csh ^ (((r0 + 0) & 7) << 4))) = (u16)p01;
      *(u16*)((char*)P + (r0 + 1) * 512 + (csh ^ (((r0 + 1) & 7) << 4))) = (u16)(p01 >> 16);
      *(u16*)((char*)P + (r0 + 2) * 512 + (csh ^ (((r0 + 2) & 7) << 4))) = (u16)p23;
      *(u16*)((char*)P + (r0 + 3) * 512 + (csh ^ (((r0 + 3) & 7) << 4))) = (u16)(p23 >> 16);
    }
  }
}

// One f(z) evaluation; z (bf16, node-major, stride 256B, swizzled) in P on entry.
// ZERO persistent register state. RK state in ws slabs (per-thread coalesced):
//   SA: y -> V -> W -> yn      SB: k1 -> U
template <int E>
__device__ __forceinline__ void feval(int step,
    u16* P, u16* Q, const u16* As,
    const u16* __restrict__ W1T, const u16* __restrict__ W2T, const u16* __restrict__ W3T,
    const float* __restrict__ b1, const float* __restrict__ b2, const float* __restrict__ b3,
    f32x4* __restrict__ SA, f32x4* __restrict__ SB,
    float* __restrict__ out,
    int batch, int tid, int lane, int mb, int wn) {
  const int l15 = lane & 15, lg = lane >> 4;

  // stage 1: t1 = z @ W1   [M128 N256 K128] -> Q (t^T)
#pragma unroll 1
  for (int h = 0; h < 2; ++h) {
    f32x4 acc[4][2];
    gemm2<4, false>(acc, P, 256, mb, W1T, 128, wn * 64 + h * 32);
    epi_T2(acc, Q, wn * 64 + h * 32, mb, lane);
  }
  __syncthreads();
  // stage 2: h1 = tanh(A @ t1 + b1) -> P node-major (stride 512)
#pragma unroll 1
  for (int h = 0; h < 2; ++h) {
    f32x4 acc[4][2];
    gemm2<4, true>(acc, As, 256, mb, Q, 0, wn * 64 + h * 32);
    epi_H2(acc, P, b1, wn * 64 + h * 32, mb, lane);
  }
  __syncthreads();
  // stage 3: t2 = h1 @ W2  [M128 N256 K256] -> Q (t^T)
#pragma unroll 1
  for (int h = 0; h < 2; ++h) {
    f32x4 acc[4][2];
    gemm2<8, false>(acc, P, 512, mb, W2T, 256, wn * 64 + h * 32);
    epi_T2(acc, Q, wn * 64 + h * 32, mb, lane);
  }
  __syncthreads();
  // stage 4: h2 = tanh(A @ t2 + b2) -> P node-major
#pragma unroll 1
  for (int h = 0; h < 2; ++h) {
    f32x4 acc[4][2];
    gemm2<4, true>(acc, As, 256, mb, Q, 0, wn * 64 + h * 32);
    epi_H2(acc, P, b2, wn * 64 + h * 32, mb, lane);
  }
  __syncthreads();
  { // stage 5: t3 = h2 @ W3  [M128 N128 K256] -> Q rows 0..127
    f32x4 acc[4][2];
    gemm2<8, false>(acc, P, 512, mb, W3T, 256, wn * 32);
    epi_T2(acc, Q, wn * 32, mb, lane);
  }
  __syncthreads();

  // stage 6: k = A @ t3 + b3 [M128 N128 K128] + fused RK epilogue
#pragma unroll 1
  for (int p = 0; p < 2; ++p) {
    f32x4 ya[4], ba[4];
#pragma unroll
    for (int q = 0; q < 4; ++q) ya[q] = SA[(p * 4 + q) * 512 + tid];
    if constexpr (E == 2 || E == 3) {
#pragma unroll
      for (int q = 0; q < 4; ++q) ba[q] = SB[(p * 4 + q) * 512 + tid];
    }
    f32x4 acc[4];
    gemm1<4, true>(acc, As, 256, mb, Q, 0, wn * 32 + p * 16);
    const int c = wn * 32 + p * 16 + l15;
    const float bb = b3[c];
    const int cz = c << 1;
#pragma unroll
    for (int mt = 0; mt < 4; ++mt) {
      f32x4 v = acc[mt];
      const int r0 = mb + mt * 16 + (lg << 2);
      const int i4 = p * 4 + mt;
      f32x4 wa, wb, zv;
#pragma unroll
      for (int e = 0; e < 4; ++e) {
        const int r = r0 + e;
        const float kv = v[e] + bb;
        float z;
        if constexpr (E == 1) {
          wb[e] = kv;                                   // k1 -> SB
          z = ya[mt][e] + (DT_ * (1.0f / 3.0f)) * kv;
        } else if constexpr (E == 2) {
          const float k1 = ba[mt][e];
          const float y = ya[mt][e];
          z = y + DT_ * (kv - k1 * (1.0f / 3.0f));
          wb[e] = y + DT_ * (k1 - kv);                  // U -> SB
          wa[e] = y + (DT_ * 0.125f) * (k1 + 3.0f * kv);  // V -> SA
        } else if constexpr (E == 3) {
          z = ba[mt][e] + DT_ * kv;                     // z4 = U + dt*k3
          wa[e] = ya[mt][e] + (DT_ * 0.375f) * kv;      // W -> SA
        } else {
          const float yn = ya[mt][e] + (DT_ * 0.125f) * kv;
          wa[e] = yn;                                   // yn -> SA
          __builtin_nontemporal_store(yn, &out[batch * 163840 + r * 1280 + (step + 1) * 128 + c]);
          z = yn;
        }
        zv[e] = z;
      }
      const u32 z01 = cvtpk(zv.x, zv.y);
      const u32 z23 = cvtpk(zv.z, zv.w);
      *(u16*)((char*)P + (r0 + 0) * 256 + (cz ^ (((r0 + 0) & 7) << 4))) = (u16)z01;
      *(u16*)((char*)P + (r0 + 1) * 256 + (cz ^ (((r0 + 1) & 7) << 4))) = (u16)(z01 >> 16);
      *(u16*)((char*)P + (r0 + 2) * 256 + (cz ^ (((r0 + 2) & 7) << 4))) = (u16)z23;
      *(u16*)((char*)P + (r0 + 3) * 256 + (cz ^ (((r0 + 3) & 7) << 4))) = (u16)(z23 >> 16);
      if constexpr (E == 1 || E == 2) SB[i4 * 512 + tid] = wb;
      if constexpr (E != 1) SA[i4 * 512 + tid] = wa;
    }
  }
  __syncthreads();
}

__global__ __launch_bounds__(512, 2)  // 8-wave block, 1 block/CU -> 2 waves/EU
void ode_main(
    const u16* __restrict__ Aswz,
    const u16* __restrict__ W1T, const u16* __restrict__ W2T, const u16* __restrict__ W3T,
    const float* __restrict__ b1, const float* __restrict__ b2, const float* __restrict__ b3,
    const float* __restrict__ x,
    f32x4* __restrict__ KS,
    float* __restrict__ out) {
  __shared__ u16 P[32768];   // 64 KB: activations node-major / z
  __shared__ u16 Q[32768];   // 64 KB: transposed intermediates t^T
  __shared__ u16 As[16384];  // 32 KB: normalized adjacency, pre-swizzled
  const int tid = threadIdx.x;
  const int lane = tid & 63;
  const int wid = tid >> 6;
  const int wm = wid >> 2, wn = wid & 3;
  const int mb = wm * 64;
  const int l15 = lane & 15, lg = lane >> 4;
  const int batch = blockIdx.x;
  f32x4* SA = KS + batch * 8192;       // 64 KB slab: y / V / W / yn
  f32x4* SB = SA + 4096;               // 64 KB slab: k1 / U

  { // stage adjacency into LDS (pre-swizzled in ws -> linear copy); 2048 uint4
    const uint4* s = (const uint4*)Aswz;
    uint4* d = (uint4*)As;
#pragma unroll
    for (int i = 0; i < 4; ++i) d[tid + i * 512] = s[tid + i * 512];
  }

  // init: y0 -> SA slab; seed z into P; write out step-0 slot. No persistent regs.
#pragma unroll 1
  for (int p = 0; p < 2; ++p)
#pragma unroll 1
    for (int mt = 0; mt < 4; ++mt) {
      const int c = wn * 32 + p * 16 + l15;
      f32x4 w;
#pragma unroll
      for (int e = 0; e < 4; ++e) {
        const int r = mb + mt * 16 + (lg << 2) + e;
        const float v = x[((batch * 128 + r) * 12 + 11) * 128 + c];
        w[e] = v;
        __builtin_nontemporal_store(v, &out[batch * 163840 + r * 1280 + c]);
        *(u16*)((char*)P + r * 256 + ((c << 1) ^ ((r & 7) << 4))) = f2bf(v);
      }
      SA[(p * 4 + mt) * 512 + tid] = w;
    }
  __syncthreads();

  for (int s = 0; s < 9; ++s) {
    feval<1>(s, P, Q, As, W1T, W2T, W3T, b1, b2, b3, SA, SB, out, batch, tid, lane, mb, wn);
    feval<2>(s, P, Q, As, W1T, W2T, W3T, b1, b2, b3, SA, SB, out, batch, tid, lane, mb, wn);
    feval<3>(s, P, Q, As, W1T, W2T, W3T, b1, b2, b3, SA, SB, out, batch, tid, lane, mb, wn);
    feval<4>(s, P, Q, As, W1T, W2T, W3T, b1, b2, b3, SA, SB, out, batch, tid, lane, mb, wn);
  }
}

// ---- prep kernels ----

__global__ void prep_adj_k(const float* __restrict__ adjw, u16* __restrict__ Aswz) {
  const int n = blockIdx.x;
  const int m = threadIdx.x;  // 128 threads = 2 waves
  const float w = adjw[n * 128 + m];
  const float sg = 1.0f / (1.0f + __expf(-w));
  float s = sg;
#pragma unroll
  for (int o = 1; o < 64; o <<= 1) s += __shfl_xor(s, o);
  __shared__ float red[2];
  if ((m & 63) == 0) red[m >> 6] = s;
  __syncthreads();
  const float deg = fmaxf(red[0] + red[1], 1.0f);
  const float v = sg / deg;
  *(u16*)((char*)Aswz + n * 256 + ((m << 1) ^ ((n & 7) << 4))) = f2bf(v);
}

__global__ void prep_w_k(const float* __restrict__ W1, const float* __restrict__ W2,
                         const float* __restrict__ W3,
                         u16* __restrict__ W1T, u16* __restrict__ W2T, u16* __restrict__ W3T) {
  const int i = blockIdx.x * 256 + threadIdx.x;
  if (i < 32768) {
    W1T[i] = f2bf(W1[(i & 127) * 256 + (i >> 7)]);  // W1T[hid][f] = W1[f][hid]
    W3T[i] = f2bf(W3[(i & 255) * 128 + (i >> 8)]);  // W3T[f][hid] = W3[hid][f]
  }
  if (i < 65536) W2T[i] = f2bf(W2[(i & 255) * 256 + (i >> 8)]);  // W2T[h2][h1] = W2[h1][h2]
}

extern "C" void kernel_launch(void* const* d_in, const int* in_sizes, int n_in,
                              void* d_out, int out_size, void* d_ws, size_t ws_size,
                              hipStream_t stream) {
  const float* x    = (const float*)d_in[0];
  const float* adjw = (const float*)d_in[1];
  const float* W1   = (const float*)d_in[2];
  const float* b1   = (const float*)d_in[3];
  const float* W2   = (const float*)d_in[4];
  const float* b2   = (const float*)d_in[5];
  const float* W3   = (const float*)d_in[6];
  const float* b3   = (const float*)d_in[7];
  float* out = (float*)d_out;

  u16* Aswz = (u16*)d_ws;
  u16* W1T = Aswz + 16384;
  u16* W2T = W1T + 32768;
  u16* W3T = W2T + 65536;
  f32x4* KS = (f32x4*)(W3T + 32768);  // 128 blocks x 128 KB = 16 MB RK state slabs

  prep_adj_k<<<128, 128, 0, stream>>>(adjw, Aswz);
  prep_w_k<<<256, 256, 0, stream>>>(W1, W2, W3, W1T, W2T, W3T);
  ode_main<<<128, 512, 0, stream>>>(Aswz, W1T, W2T, W3T, b1, b2, b3, x, KS, out);
}